// Round 8
// baseline (4809.733 us; speedup 1.0000x reference)
//
#include <hip/hip_runtime.h>
#include <math.h>

#define BATCH 1024
#define IN_F  1024
#define OUT_F 2048
#define LAMBD 0.2f
#define TOL   1e-4f
#define MAX_ITERS 100

#define BSCALE 32.0f
#define BSCALE_INV 0.03125f
#define PNHALF (BATCH * 32)   // floats per pnorm parity buffer: [1024][16][2]

typedef _Float16 half8 __attribute__((ext_vector_type(8)));
typedef _Float16 half4 __attribute__((ext_vector_type(4)));
typedef float    floatx16 __attribute__((ext_vector_type(16)));
typedef unsigned char fp8_t;

#define GLOAD_LDS16(g, l) __builtin_amdgcn_global_load_lds(              \
    (const __attribute__((address_space(1))) void*)(g),                  \
    (__attribute__((address_space(3))) void*)(l), 16, 0, 0)

// fp8 e4m3 (OCP on gfx950) HW converts
__device__ inline int pk4_fp8(float a, float b, float c, float d) {
    int w = __builtin_amdgcn_cvt_pk_fp8_f32(a, b, 0, false);
    w = __builtin_amdgcn_cvt_pk_fp8_f32(c, d, w, true);
    return w;
}
__device__ inline fp8_t enc_fp8(float a) {
    return (fp8_t)(__builtin_amdgcn_cvt_pk_fp8_f32(a, a, 0, false) & 0xff);
}
__device__ inline void cvt4_fp8(int w, float o[4]) {
    o[0] = __builtin_amdgcn_cvt_f32_fp8(w, 0);
    o[1] = __builtin_amdgcn_cvt_f32_fp8(w, 1);
    o[2] = __builtin_amdgcn_cvt_f32_fp8(w, 2);
    o[3] = __builtin_amdgcn_cvt_f32_fp8(w, 3);
}

// ---------------------------------------------------------------------------
// Merged setup kernel (proven R5-R7): block ranges do
//   [0,2048)      init: zero v,u (f16), enc (f32), solved, pnorm
//   [2048,3072)   cast x  f32->f16
//   [3072,5120)   cast w  f32->f16
//   [5120,7168)   transpose w -> whT f16 [IN_F][OUT_F]
//   [7168,11264)  transpose+fp8(x32) Minv -> BhT fp8 [n][k]
// ---------------------------------------------------------------------------
#define NB_INIT 2048
#define NB_CX   1024
#define NB_CW   2048
#define NB_TW   2048
#define NB_SB   4096
#define NB_TOTAL (NB_INIT + NB_CX + NB_CW + NB_TW + NB_SB)

__global__ __launch_bounds__(256)
void setup_kernel(const float* __restrict__ x, const float* __restrict__ w,
                  const float* __restrict__ Minv,
                  float4* __restrict__ v16, float4* __restrict__ u16,
                  float4* __restrict__ enc4, int* __restrict__ solved,
                  float4* __restrict__ pn4,
                  _Float16* __restrict__ xh, _Float16* __restrict__ wh,
                  _Float16* __restrict__ whT, fp8_t* __restrict__ BhT) {
    const int b = blockIdx.x;
    const int tid = threadIdx.x;
    __shared__ float tile[32][33];

    if (b < NB_INIT) {
        const int idx = b * 256 + tid;          // 0 .. 524287
        const float4 z = make_float4(0.f, 0.f, 0.f, 0.f);
        enc4[idx] = z;                          // P/4 float4
        if (idx < BATCH * OUT_F / 8) { v16[idx] = z; u16[idx] = z; }
        if (idx < BATCH) solved[idx] = 0;
        if (idx < 2 * PNHALF / 4) pn4[idx] = z; // both pnorm parity buffers
        return;
    }
    if (b < NB_INIT + NB_CX) {
        const int i = ((b - NB_INIT) * 256 + tid) * 4;
        const float4 f = *(const float4*)&x[i];
        half4 h;
        h[0] = (_Float16)f.x; h[1] = (_Float16)f.y;
        h[2] = (_Float16)f.z; h[3] = (_Float16)f.w;
        *(half4*)&xh[i] = h;
        return;
    }
    if (b < NB_INIT + NB_CX + NB_CW) {
        const int i = ((b - NB_INIT - NB_CX) * 256 + tid) * 4;
        const float4 f = *(const float4*)&w[i];
        half4 h;
        h[0] = (_Float16)f.x; h[1] = (_Float16)f.y;
        h[2] = (_Float16)f.z; h[3] = (_Float16)f.w;
        *(half4*)&wh[i] = h;
        return;
    }
    if (b < NB_INIT + NB_CX + NB_CW + NB_TW) {
        const int lb = b - NB_INIT - NB_CX - NB_CW;
        const int bx = lb & 31;
        const int by = lb >> 5;
        const int row0 = by * 32;
        const int col0 = bx * 32;
        const int r = tid >> 3;
        const int c4 = (tid & 7) * 4;
        const float4 b4 = *(const float4*)&w[(size_t)(row0 + r) * IN_F + col0 + c4];
        tile[r][c4 + 0] = b4.x; tile[r][c4 + 1] = b4.y;
        tile[r][c4 + 2] = b4.z; tile[r][c4 + 3] = b4.w;
        __syncthreads();
        half4 h;
#pragma unroll
        for (int j = 0; j < 4; ++j) h[j] = (_Float16)tile[c4 + j][r];
        *(half4*)&whT[(size_t)(col0 + r) * OUT_F + row0 + c4] = h;
        return;
    }
    {
        const int lb = b - NB_INIT - NB_CX - NB_CW - NB_TW;
        const int bx = lb & 63;
        const int by = lb >> 6;
        const int k0 = by * 32;
        const int n0 = bx * 32;
        const int r = tid >> 3;
        const int c4 = (tid & 7) * 4;
        const float4 b4 = *(const float4*)&Minv[(size_t)(k0 + r) * OUT_F + n0 + c4];
        tile[r][c4 + 0] = b4.x; tile[r][c4 + 1] = b4.y;
        tile[r][c4 + 2] = b4.z; tile[r][c4 + 3] = b4.w;
        __syncthreads();
        const int wrd = pk4_fp8(tile[c4 + 0][r] * BSCALE, tile[c4 + 1][r] * BSCALE,
                                tile[c4 + 2][r] * BSCALE, tile[c4 + 3][r] * BSCALE);
        *(int*)&BhT[(size_t)(n0 + r) * OUT_F + k0 + c4] = wrd;
    }
}

// ---------------------------------------------------------------------------
// fp16 MFMA NT GEMM (one-shot, R7 counted-vmcnt dbuf, proven):
// Ab = x @ w^T -> Ab8 fp8 + initial Aeff fp8 (into Ah0; v=u=0).
// ---------------------------------------------------------------------------
__global__ __launch_bounds__(256)
void mfma_nt_ab(const _Float16* __restrict__ A, const _Float16* __restrict__ B,
                fp8_t* __restrict__ Ab8, fp8_t* __restrict__ Ah,
                int N, int K) {
    __shared__ _Float16 smem[2][8192];
    const int tid = threadIdx.x;
    const int m0 = blockIdx.y * 128;
    const int n0 = blockIdx.x * 128;
    const int wv = tid >> 6, ln = tid & 63;
    const int half = ln >> 5, l31 = ln & 31;
    const int wm = (wv >> 1) * 64, wn = (wv & 1) * 64;
    const int r0 = tid >> 2, koff = (tid & 3) * 8;
    const size_t ga0 = (size_t)(m0 + r0) * K + koff;
    const size_t ga1 = (size_t)(m0 + r0 + 64) * K + koff;
    const size_t gb0 = (size_t)(n0 + r0) * K + koff;
    const size_t gb1 = (size_t)(n0 + r0 + 64) * K + koff;
    const int ldst0 = tid * 8, ldst1 = (256 + tid) * 8;

    floatx16 acc[2][2];
#pragma unroll
    for (int a = 0; a < 2; ++a)
#pragma unroll
        for (int b = 0; b < 2; ++b)
#pragma unroll
            for (int q = 0; q < 16; ++q) acc[a][b][q] = 0.f;

    GLOAD_LDS16(A + ga0, smem[0] + ldst0);
    GLOAD_LDS16(A + ga1, smem[0] + ldst1);
    GLOAD_LDS16(B + gb0, smem[0] + 4096 + ldst0);
    GLOAD_LDS16(B + gb1, smem[0] + 4096 + ldst1);
    __syncthreads();

    const int NS = K >> 5;
#pragma unroll 1
    for (int s = 0; s < NS; ++s) {
        if (s + 1 < NS) {
            _Float16* nb = smem[(s & 1) ^ 1];
            const int k = (s + 1) * 32;
            GLOAD_LDS16(A + ga0 + k, nb + ldst0);
            GLOAD_LDS16(A + ga1 + k, nb + ldst1);
            GLOAD_LDS16(B + gb0 + k, nb + 4096 + ldst0);
            GLOAD_LDS16(B + gb1 + k, nb + 4096 + ldst1);
        }
        __syncthreads();
        const _Float16* sA = smem[s & 1];
        const _Float16* sB = smem[s & 1] + 4096;
#pragma unroll
        for (int kk = 0; kk < 2; ++kk) {
            const int ko = kk * 16 + half * 8;
            const half8 a0 = *(const half8*)&sA[(wm + l31) * 32 + ko];
            const half8 a1 = *(const half8*)&sA[(wm + 32 + l31) * 32 + ko];
            const half8 b0 = *(const half8*)&sB[(wn + l31) * 32 + ko];
            const half8 b1 = *(const half8*)&sB[(wn + 32 + l31) * 32 + ko];
            acc[0][0] = __builtin_amdgcn_mfma_f32_32x32x16_f16(a0, b0, acc[0][0], 0, 0, 0);
            acc[0][1] = __builtin_amdgcn_mfma_f32_32x32x16_f16(a0, b1, acc[0][1], 0, 0, 0);
            acc[1][0] = __builtin_amdgcn_mfma_f32_32x32x16_f16(a1, b0, acc[1][0], 0, 0, 0);
            acc[1][1] = __builtin_amdgcn_mfma_f32_32x32x16_f16(a1, b1, acc[1][1], 0, 0, 0);
        }
        __syncthreads();
    }
#pragma unroll
    for (int mm = 0; mm < 2; ++mm)
#pragma unroll
        for (int nn = 0; nn < 2; ++nn) {
            const int col = n0 + wn + nn * 32 + l31;
#pragma unroll
            for (int q = 0; q < 16; ++q) {
                const int row = m0 + wm + mm * 32 + (q & 3) + 8 * (q >> 2) + 4 * half;
                const size_t o = (size_t)row * N + col;
                const fp8_t e = enc_fp8(acc[mm][nn][q]);
                Ab8[o] = e;
                Ah[o] = e;     // initial Aeff (v=u=0) -> Ah buffer 0
            }
        }
}

// ---------------------------------------------------------------------------
// fp16 MFMA GEMM (one-shot): dec = enc @ w via A=ench, B=whT (K-major)
// ---------------------------------------------------------------------------
__global__ __launch_bounds__(256)
void mfma_nn_dec(const _Float16* __restrict__ A, const _Float16* __restrict__ B,
                 float* __restrict__ C, int N, int K) {
    __shared__ _Float16 smem[2][8192];
    const int tid = threadIdx.x;
    const int m0 = blockIdx.y * 128;
    const int n0 = blockIdx.x * 128;
    const int wv = tid >> 6, ln = tid & 63;
    const int half = ln >> 5, l31 = ln & 31;
    const int wm = (wv >> 1) * 64, wn = (wv & 1) * 64;
    const int r0 = tid >> 2, koff = (tid & 3) * 8;
    const size_t ga0 = (size_t)(m0 + r0) * K + koff;
    const size_t ga1 = (size_t)(m0 + r0 + 64) * K + koff;
    const size_t gb0 = (size_t)(n0 + r0) * K + koff;
    const size_t gb1 = (size_t)(n0 + r0 + 64) * K + koff;
    const int ldst0 = tid * 8, ldst1 = (256 + tid) * 8;

    floatx16 acc[2][2];
#pragma unroll
    for (int a = 0; a < 2; ++a)
#pragma unroll
        for (int b = 0; b < 2; ++b)
#pragma unroll
            for (int q = 0; q < 16; ++q) acc[a][b][q] = 0.f;

    GLOAD_LDS16(A + ga0, smem[0] + ldst0);
    GLOAD_LDS16(A + ga1, smem[0] + ldst1);
    GLOAD_LDS16(B + gb0, smem[0] + 4096 + ldst0);
    GLOAD_LDS16(B + gb1, smem[0] + 4096 + ldst1);
    __syncthreads();

    const int NS = K >> 5;
#pragma unroll 1
    for (int s = 0; s < NS; ++s) {
        if (s + 1 < NS) {
            _Float16* nb = smem[(s & 1) ^ 1];
            const int k = (s + 1) * 32;
            GLOAD_LDS16(A + ga0 + k, nb + ldst0);
            GLOAD_LDS16(A + ga1 + k, nb + ldst1);
            GLOAD_LDS16(B + gb0 + k, nb + 4096 + ldst0);
            GLOAD_LDS16(B + gb1 + k, nb + 4096 + ldst1);
        }
        __syncthreads();
        const _Float16* sA = smem[s & 1];
        const _Float16* sB = smem[s & 1] + 4096;
#pragma unroll
        for (int kk = 0; kk < 2; ++kk) {
            const int ko = kk * 16 + half * 8;
            const half8 a0 = *(const half8*)&sA[(wm + l31) * 32 + ko];
            const half8 a1 = *(const half8*)&sA[(wm + 32 + l31) * 32 + ko];
            const half8 b0 = *(const half8*)&sB[(wn + l31) * 32 + ko];
            const half8 b1 = *(const half8*)&sB[(wn + 32 + l31) * 32 + ko];
            acc[0][0] = __builtin_amdgcn_mfma_f32_32x32x16_f16(a0, b0, acc[0][0], 0, 0, 0);
            acc[0][1] = __builtin_amdgcn_mfma_f32_32x32x16_f16(a0, b1, acc[0][1], 0, 0, 0);
            acc[1][0] = __builtin_amdgcn_mfma_f32_32x32x16_f16(a1, b0, acc[1][0], 0, 0, 0);
            acc[1][1] = __builtin_amdgcn_mfma_f32_32x32x16_f16(a1, b1, acc[1][1], 0, 0, 0);
        }
        __syncthreads();
    }
#pragma unroll
    for (int mm = 0; mm < 2; ++mm)
#pragma unroll
        for (int nn = 0; nn < 2; ++nn) {
            const int col = n0 + wn + nn * 32 + l31;
#pragma unroll
            for (int q = 0; q < 16; ++q) {
                const int row = m0 + wm + mm * 32 + (q & 3) + 8 * (q >> 2) + 4 * half;
                C[(size_t)row * N + col] = acc[mm][nn][q];
            }
        }
}

// ---------------------------------------------------------------------------
// FUSED per-iteration kernel: ONE dispatch per ADMM iteration.
// Grid (16 col-tiles, 8 row-stripes), 256 thr. Block (bx,by):
//  (a) decision: per row of the stripe, reduce prev-iter pnorm partials
//      (fixed order), freeze newly-converged rows (persist Ah slice to the
//      next parity buffer). Redundant across bx blocks; idempotent.
//  (b) GEMM: xk slice [128 rows][128 cols] over FULL K=2048 (BK=128) from
//      AhCur (written only at t-1 -> no intra-dispatch races) and BhT.
//  (c) update: block-local slice update of v,u,AhNxt,enc; per-slice norm
//      partials -> pnCur. enc written every active iteration (holds v_new
//      of the row's last update == reference v_sol at freeze).
// ---------------------------------------------------------------------------
__global__ __launch_bounds__(256)
void fused_iter(const fp8_t* __restrict__ AhCur, fp8_t* __restrict__ AhNxt,
                const fp8_t* __restrict__ BhT, const fp8_t* __restrict__ Ab8,
                _Float16* __restrict__ v, _Float16* __restrict__ u,
                float* __restrict__ enc, int* __restrict__ solved,
                const float* __restrict__ pnPrev, float* __restrict__ pnCur) {
    __shared__ __align__(16) fp8_t smem[65536];   // staging 32KB -> f32 tile 64KB
    __shared__ int s_flags[128];
    __shared__ int s_active;

    const int tid = threadIdx.x;
    const int bx = blockIdx.x;
    const int by = blockIdx.y;
    const int m0 = by * 128;
    const int n0 = bx * 128;

    // ================= (a) decisions for iter t-1 =================
    if (tid == 0) s_active = 0;
    __syncthreads();
    if (tid < 128) {
        const int row = m0 + tid;
        int act = 0;
        if (solved[row] == 0) {
            const float* pp = pnPrev + row * 32;
            float dx2 = 0.f, xn2 = 0.f;
#pragma unroll
            for (int j = 0; j < 16; ++j) { dx2 += pp[2 * j]; xn2 += pp[2 * j + 1]; }
            const bool conv = (sqrtf(dx2) / sqrtf(xn2)) < TOL;  // NaN->false
            if (conv) {
                solved[row] = 1;                 // idempotent across bx blocks
                // persist frozen Ah slice into next parity buffer
                const int4* src = (const int4*)(AhCur + (size_t)row * OUT_F + n0);
                int4* dst = (int4*)(AhNxt + (size_t)row * OUT_F + n0);
#pragma unroll
                for (int j = 0; j < 8; ++j) dst[j] = src[j];
            } else {
                act = 1;
                s_active = 1;                    // benign concurrent LDS stores
            }
        }
        s_flags[tid] = act;
    }
    __syncthreads();
    if (!s_active) return;

    // ================= (b) full-K GEMM =================
    const int wv = tid >> 6;
    const int ln = tid & 63;
    const int half = ln >> 5;
    const int l31 = ln & 31;
    const int wm = (wv >> 1) * 64;
    const int wn = (wv & 1) * 64;

    const int r = tid & 127;
    const int c0 = tid >> 7;          // 0 or 1
    const fp8_t* gA = AhCur + (size_t)(m0 + r) * OUT_F;
    const fp8_t* gB = BhT + (size_t)(n0 + r) * OUT_F;
    const int d0 = ((c0 + 0) * 128 + r) * 16;
    const int d1 = ((c0 + 2) * 128 + r) * 16;
    const int d2 = ((c0 + 4) * 128 + r) * 16;
    const int d3 = ((c0 + 6) * 128 + r) * 16;

    floatx16 acc[2][2];
#pragma unroll
    for (int a = 0; a < 2; ++a)
#pragma unroll
        for (int b = 0; b < 2; ++b)
#pragma unroll
            for (int q = 0; q < 16; ++q) acc[a][b][q] = 0.f;

    const int ao0 = (wm + l31) * 16 + half * 8;
    const int ao1 = (wm + 32 + l31) * 16 + half * 8;
    const int bo0 = (wn + l31) * 16 + half * 8;
    const int bo1 = (wn + 32 + l31) * 16 + half * 8;

#pragma unroll 1
    for (int kb = 0; kb < OUT_F / 128; ++kb) {    // 16 steps, BK=128
        const int ko = kb * 128;
        __syncthreads();
        GLOAD_LDS16(gA + ko + (c0 + 0) * 16, smem + d0);
        GLOAD_LDS16(gA + ko + (c0 + 2) * 16, smem + d1);
        GLOAD_LDS16(gA + ko + (c0 + 4) * 16, smem + d2);
        GLOAD_LDS16(gA + ko + (c0 + 6) * 16, smem + d3);
        GLOAD_LDS16(gB + ko + (c0 + 0) * 16, smem + 16384 + d0);
        GLOAD_LDS16(gB + ko + (c0 + 2) * 16, smem + 16384 + d1);
        GLOAD_LDS16(gB + ko + (c0 + 4) * 16, smem + 16384 + d2);
        GLOAD_LDS16(gB + ko + (c0 + 6) * 16, smem + 16384 + d3);
        __syncthreads();
#pragma unroll
        for (int kk = 0; kk < 8; ++kk) {
            const int cb = kk * 2048;
            const long long a0 = *(const long long*)&smem[cb + ao0];
            const long long a1 = *(const long long*)&smem[cb + ao1];
            const long long b0 = *(const long long*)&smem[16384 + cb + bo0];
            const long long b1 = *(const long long*)&smem[16384 + cb + bo1];
            acc[0][0] = __builtin_amdgcn_mfma_f32_32x32x16_fp8_fp8(a0, b0, acc[0][0], 0, 0, 0);
            acc[0][1] = __builtin_amdgcn_mfma_f32_32x32x16_fp8_fp8(a0, b1, acc[0][1], 0, 0, 0);
            acc[1][0] = __builtin_amdgcn_mfma_f32_32x32x16_fp8_fp8(a1, b0, acc[1][0], 0, 0, 0);
            acc[1][1] = __builtin_amdgcn_mfma_f32_32x32x16_fp8_fp8(a1, b1, acc[1][1], 0, 0, 0);
        }
    }

    // scatter f32 xk tile into LDS (XOR-swizzled to avoid bank conflicts)
    __syncthreads();
    float* ftile = (float*)smem;                  // [128][128] f32, 64KB
#pragma unroll
    for (int mm = 0; mm < 2; ++mm)
#pragma unroll
        for (int nn = 0; nn < 2; ++nn) {
            const int lcol = wn + nn * 32 + l31;
#pragma unroll
            for (int q = 0; q < 16; ++q) {
                const int lrow = wm + mm * 32 + (q & 3) + 8 * (q >> 2) + 4 * half;
                ftile[lrow * 128 + (lcol ^ (lrow & 31))] = acc[mm][nn][q] * BSCALE_INV;
            }
        }
    __syncthreads();

    // ================= (c) block-local update =================
    const int urow = tid >> 1;
    if (s_flags[urow]) {
        const int row = m0 + urow;
        const int cb = (tid & 1) * 64;
        const size_t off = (size_t)row * OUT_F + n0 + cb;
        const float* ft = ftile + urow * 128;
        const int rx = urow & 31;
        float dx2 = 0.f, xn2 = 0.f;
#pragma unroll
        for (int j8 = 0; j8 < 8; ++j8) {
            const size_t o8 = off + j8 * 8;
            const half8 u8 = *(const half8*)&u[o8];
            const half8 v8 = *(const half8*)&v[o8];
            const int2 ab2 = *(const int2*)&Ab8[o8];
            float ab[8];
            cvt4_fp8(ab2.x, ab); cvt4_fp8(ab2.y, ab + 4);
            half8 vo, uo;
            float vn[8], ae[8];
#pragma unroll
            for (int j = 0; j < 8; ++j) {
                const float xk = ft[(cb + j8 * 8 + j) ^ rx];
                const float uv = (float)u8[j];
                const float vp = (float)v8[j];
                const float z = xk + uv;
                const float az = fabsf(z) - LAMBD;
                const float vnew = az > 0.f ? copysignf(az, z) : 0.f;
                const float unew = uv + xk - vnew;
                const float d = vnew - vp;
                dx2 += d * d;
                xn2 += vnew * vnew;
                vn[j] = vnew;
                vo[j] = (_Float16)vnew;
                uo[j] = (_Float16)unew;
                ae[j] = ab[j] + vnew - unew;
            }
            *(half8*)&v[o8] = vo;
            *(half8*)&u[o8] = uo;
            int2 ah;
            ah.x = pk4_fp8(ae[0], ae[1], ae[2], ae[3]);
            ah.y = pk4_fp8(ae[4], ae[5], ae[6], ae[7]);
            *(int2*)&AhNxt[o8] = ah;
            *(float4*)&enc[o8] = make_float4(vn[0], vn[1], vn[2], vn[3]);
            *(float4*)&enc[o8 + 4] = make_float4(vn[4], vn[5], vn[6], vn[7]);
        }
        dx2 += __shfl_xor(dx2, 1);
        xn2 += __shfl_xor(xn2, 1);
        if ((tid & 1) == 0) {
            pnCur[row * 32 + bx * 2] = dx2;
            pnCur[row * 32 + bx * 2 + 1] = xn2;
        }
    }
}

// ---------------------------------------------------------------------------
// Finalize: apply iter-99 convergence decisions (enc already holds v_new(99)).
// ---------------------------------------------------------------------------
__global__ __launch_bounds__(256)
void finalize_kernel(const float* __restrict__ pn, int* __restrict__ solved) {
    const int row = blockIdx.x * 256 + threadIdx.x;
    if (row < BATCH && solved[row] == 0) {
        const float* pp = pn + row * 32;
        float dx2 = 0.f, xn2 = 0.f;
#pragma unroll
        for (int j = 0; j < 16; ++j) { dx2 += pp[2 * j]; xn2 += pp[2 * j + 1]; }
        if ((sqrtf(dx2) / sqrtf(xn2)) < TOL) solved[row] = 1;
    }
}

// ---------------------------------------------------------------------------
// cast enc->f16 for the dec GEMM; zero both for never-converged rows
// (reference leaves v_sol = 0 for rows that never converge).
// ---------------------------------------------------------------------------
__global__ __launch_bounds__(256)
void cast_zero_kernel(float* __restrict__ enc, _Float16* __restrict__ out,
                      const int* __restrict__ solved) {
    const int i = (blockIdx.x * 256 + threadIdx.x) * 4;
    const int row = i >> 11;                      // OUT_F = 2048
    float4 f;
    if (solved[row]) {
        f = *(const float4*)&enc[i];
    } else {
        f = make_float4(0.f, 0.f, 0.f, 0.f);
        *(float4*)&enc[i] = f;
    }
    half4 h;
    h[0] = (_Float16)f.x; h[1] = (_Float16)f.y;
    h[2] = (_Float16)f.z; h[3] = (_Float16)f.w;
    *(half4*)&out[i] = h;
}

// ---------------------------------------------------------------------------
extern "C" void kernel_launch(void* const* d_in, const int* in_sizes, int n_in,
                              void* d_out, int out_size, void* d_ws, size_t ws_size,
                              hipStream_t stream) {
    (void)in_sizes; (void)n_in; (void)out_size; (void)ws_size;
    const float* x    = (const float*)d_in[0];   // 1024 x 1024
    const float* w    = (const float*)d_in[1];   // 2048 x 1024
    const float* Minv = (const float*)d_in[2];   // 2048 x 2048

    float* enc = (float*)d_out;                  // 1024 x 2048
    float* dec = enc + (size_t)BATCH * OUT_F;    // 1024 x 1024

    constexpr size_t P = (size_t)BATCH * OUT_F;  // 2M elements
    fp8_t* Ab8 = (fp8_t*)d_ws;                   // P fp8
    _Float16* v   = (_Float16*)(Ab8 + P);        // P f16
    _Float16* u   = v + P;                       // P f16
    _Float16* xh  = u + P;                       // 1M f16
    _Float16* wh  = xh + (size_t)BATCH * IN_F;   // 2M f16
    _Float16* whT = wh + (size_t)OUT_F * IN_F;   // 2M f16
    _Float16* ench = whT + (size_t)IN_F * OUT_F; // P f16
    fp8_t* Ah0 = (fp8_t*)(ench + P);             // P fp8 (parity 0)
    fp8_t* Ah1 = Ah0 + P;                        // P fp8 (parity 1, in old xkp)
    float* pnorm = (float*)(Ah1 + P);            // 2 * PNHALF floats (256KB)
    fp8_t* BhT = Ah0 + 5 * P;                    // OUT_F^2 fp8 (4MB), old offset
    int* solved = (int*)(BhT + (size_t)OUT_F * OUT_F);

    setup_kernel<<<NB_TOTAL, 256, 0, stream>>>(
        x, w, Minv, (float4*)v, (float4*)u, (float4*)enc, solved,
        (float4*)pnorm, xh, wh, whT, BhT);

    // Ab = x @ w^T -> Ab8 fp8 + initial Aeff fp8 into Ah0
    mfma_nt_ab<<<dim3(OUT_F / 128, BATCH / 128), 256, 0, stream>>>(
        xh, wh, Ab8, Ah0, OUT_F, IN_F);

    fp8_t* ahb[2] = { Ah0, Ah1 };
    for (int it = 0; it < MAX_ITERS; ++it) {
        const int p0 = it & 1, p1 = (it + 1) & 1;
        fused_iter<<<dim3(16, 8), 256, 0, stream>>>(
            ahb[p0], ahb[p1], BhT, Ab8, v, u, enc, solved,
            pnorm + (size_t)p1 * PNHALF,     // prev partials (parity t-1)
            pnorm + (size_t)p0 * PNHALF);    // this iter's partials
    }
    // apply iter-99 decisions (its partials are in parity (99&1)=1)
    finalize_kernel<<<(BATCH + 255) / 256, 256, 0, stream>>>(
        pnorm + (size_t)((MAX_ITERS - 1) & 1) * PNHALF, solved);

    cast_zero_kernel<<<(BATCH * OUT_F / 4 + 255) / 256, 256, 0, stream>>>(
        enc, ench, solved);
    mfma_nn_dec<<<dim3(IN_F / 128, BATCH / 128), 256, 0, stream>>>(
        ench, whT, dec, IN_F, OUT_F);
}

// Round 9
// 2270.607 us; speedup vs baseline: 2.1183x; 2.1183x over previous
//
#include <hip/hip_runtime.h>
#include <math.h>

#define BATCH 1024
#define IN_F  1024
#define OUT_F 2048
#define LAMBD 0.2f
#define TOL   1e-4f
#define MAX_ITERS 100

#define KSPLIT 4
#define KCHUNK (OUT_F / KSPLIT)   // 512
#define BSCALE 32.0f
#define BSCALE_INV 0.03125f

typedef _Float16 half8 __attribute__((ext_vector_type(8)));
typedef _Float16 half4 __attribute__((ext_vector_type(4)));
typedef float    floatx16 __attribute__((ext_vector_type(16)));
typedef unsigned char fp8_t;

#define GLOAD_LDS16(g, l) __builtin_amdgcn_global_load_lds(              \
    (const __attribute__((address_space(1))) void*)(g),                  \
    (__attribute__((address_space(3))) void*)(l), 16, 0, 0)

// fp8 e4m3 (OCP on gfx950) HW converts
__device__ inline int pk4_fp8(float a, float b, float c, float d) {
    int w = __builtin_amdgcn_cvt_pk_fp8_f32(a, b, 0, false);
    w = __builtin_amdgcn_cvt_pk_fp8_f32(c, d, w, true);
    return w;
}
__device__ inline fp8_t enc_fp8(float a) {
    return (fp8_t)(__builtin_amdgcn_cvt_pk_fp8_f32(a, a, 0, false) & 0xff);
}
// byte-selector must be a literal constant -> expand all four
__device__ inline void cvt4_fp8(int w, float o[4]) {
    o[0] = __builtin_amdgcn_cvt_f32_fp8(w, 0);
    o[1] = __builtin_amdgcn_cvt_f32_fp8(w, 1);
    o[2] = __builtin_amdgcn_cvt_f32_fp8(w, 2);
    o[3] = __builtin_amdgcn_cvt_f32_fp8(w, 3);
}

// ---------------------------------------------------------------------------
// Merged setup kernel (proven R5-R8): block ranges do
//   [0,2048)      init: zero v,u (f16), enc (f32), solved; stripe flags
//   [2048,3072)   cast x  f32->f16
//   [3072,5120)   cast w  f32->f16
//   [5120,7168)   transpose w -> whT f16 [IN_F][OUT_F]
//   [7168,11264)  transpose+fp8(x32) Minv -> BhT fp8 [n][k]
// ---------------------------------------------------------------------------
#define NB_INIT 2048
#define NB_CX   1024
#define NB_CW   2048
#define NB_TW   2048
#define NB_SB   4096
#define NB_TOTAL (NB_INIT + NB_CX + NB_CW + NB_TW + NB_SB)

__global__ __launch_bounds__(256)
void setup_kernel(const float* __restrict__ x, const float* __restrict__ w,
                  const float* __restrict__ Minv,
                  float4* __restrict__ v16, float4* __restrict__ u16,
                  float4* __restrict__ enc4, int* __restrict__ solved,
                  int* __restrict__ stripe_act,
                  _Float16* __restrict__ xh, _Float16* __restrict__ wh,
                  _Float16* __restrict__ whT, fp8_t* __restrict__ BhT) {
    const int b = blockIdx.x;
    const int tid = threadIdx.x;
    __shared__ float tile[32][33];

    if (b < NB_INIT) {
        const int idx = b * 256 + tid;          // 0 .. 524287
        const float4 z = make_float4(0.f, 0.f, 0.f, 0.f);
        enc4[idx] = z;                          // P/4 float4
        if (idx < BATCH * OUT_F / 8) { v16[idx] = z; u16[idx] = z; }
        if (idx < BATCH) solved[idx] = 0;
        if (idx < 16) stripe_act[idx] = (idx < 8) ? 1 : 0;   // parity0=all-on
        return;
    }
    if (b < NB_INIT + NB_CX) {
        const int i = ((b - NB_INIT) * 256 + tid) * 4;
        const float4 f = *(const float4*)&x[i];
        half4 h;
        h[0] = (_Float16)f.x; h[1] = (_Float16)f.y;
        h[2] = (_Float16)f.z; h[3] = (_Float16)f.w;
        *(half4*)&xh[i] = h;
        return;
    }
    if (b < NB_INIT + NB_CX + NB_CW) {
        const int i = ((b - NB_INIT - NB_CX) * 256 + tid) * 4;
        const float4 f = *(const float4*)&w[i];
        half4 h;
        h[0] = (_Float16)f.x; h[1] = (_Float16)f.y;
        h[2] = (_Float16)f.z; h[3] = (_Float16)f.w;
        *(half4*)&wh[i] = h;
        return;
    }
    if (b < NB_INIT + NB_CX + NB_CW + NB_TW) {
        const int lb = b - NB_INIT - NB_CX - NB_CW;
        const int bx = lb & 31;
        const int by = lb >> 5;
        const int row0 = by * 32;
        const int col0 = bx * 32;
        const int r = tid >> 3;
        const int c4 = (tid & 7) * 4;
        const float4 b4 = *(const float4*)&w[(size_t)(row0 + r) * IN_F + col0 + c4];
        tile[r][c4 + 0] = b4.x; tile[r][c4 + 1] = b4.y;
        tile[r][c4 + 2] = b4.z; tile[r][c4 + 3] = b4.w;
        __syncthreads();
        half4 h;
#pragma unroll
        for (int j = 0; j < 4; ++j) h[j] = (_Float16)tile[c4 + j][r];
        *(half4*)&whT[(size_t)(col0 + r) * OUT_F + row0 + c4] = h;
        return;
    }
    {
        const int lb = b - NB_INIT - NB_CX - NB_CW - NB_TW;
        const int bx = lb & 63;
        const int by = lb >> 6;
        const int k0 = by * 32;
        const int n0 = bx * 32;
        const int r = tid >> 3;
        const int c4 = (tid & 7) * 4;
        const float4 b4 = *(const float4*)&Minv[(size_t)(k0 + r) * OUT_F + n0 + c4];
        tile[r][c4 + 0] = b4.x; tile[r][c4 + 1] = b4.y;
        tile[r][c4 + 2] = b4.z; tile[r][c4 + 3] = b4.w;
        __syncthreads();
        const int wrd = pk4_fp8(tile[c4 + 0][r] * BSCALE, tile[c4 + 1][r] * BSCALE,
                                tile[c4 + 2][r] * BSCALE, tile[c4 + 3][r] * BSCALE);
        *(int*)&BhT[(size_t)(n0 + r) * OUT_F + k0 + c4] = wrd;
    }
}

// ---------------------------------------------------------------------------
__global__ __launch_bounds__(256)
void cast_f16_kernel(const float* __restrict__ in, _Float16* __restrict__ out, int n) {
    const int i = (blockIdx.x * 256 + threadIdx.x) * 4;
    if (i < n) {
        const float4 f = *(const float4*)&in[i];
        half4 h;
        h[0] = (_Float16)f.x; h[1] = (_Float16)f.y;
        h[2] = (_Float16)f.z; h[3] = (_Float16)f.w;
        *(half4*)&out[i] = h;
    }
}

// ---------------------------------------------------------------------------
// fp16 MFMA NT GEMM (one-shot, exact R0 core): Ab = x @ w^T -> Ab8 fp8
// (persistent) + initial Aeff fp8 (identical, v=u=0). 128x128 tile, BK=32.
// ---------------------------------------------------------------------------
__global__ __launch_bounds__(256)
void mfma_nt_ab(const _Float16* __restrict__ A, const _Float16* __restrict__ B,
                fp8_t* __restrict__ Ab8, fp8_t* __restrict__ Ah,
                int N, int K) {
    __shared__ _Float16 sA[128 * 32];
    __shared__ _Float16 sB[128 * 32];
    const int tid = threadIdx.x;
    const int m0 = blockIdx.y * 128;
    const int n0 = blockIdx.x * 128;
    const int wv = tid >> 6, ln = tid & 63;
    const int half = ln >> 5, l31 = ln & 31;
    const int wm = (wv >> 1) * 64, wn = (wv & 1) * 64;
    const int r0 = tid >> 2, koff = (tid & 3) * 8;
    const size_t ga0 = (size_t)(m0 + r0) * K + koff;
    const size_t ga1 = (size_t)(m0 + r0 + 64) * K + koff;
    const size_t gb0 = (size_t)(n0 + r0) * K + koff;
    const size_t gb1 = (size_t)(n0 + r0 + 64) * K + koff;
    const int ldst0 = tid * 8, ldst1 = (256 + tid) * 8;

    floatx16 acc[2][2];
#pragma unroll
    for (int a = 0; a < 2; ++a)
#pragma unroll
        for (int b = 0; b < 2; ++b)
#pragma unroll
            for (int q = 0; q < 16; ++q) acc[a][b][q] = 0.f;

    for (int k = 0; k < K; k += 32) {
        __syncthreads();
        GLOAD_LDS16(A + ga0 + k, sA + ldst0);
        GLOAD_LDS16(A + ga1 + k, sA + ldst1);
        GLOAD_LDS16(B + gb0 + k, sB + ldst0);
        GLOAD_LDS16(B + gb1 + k, sB + ldst1);
        __syncthreads();
#pragma unroll
        for (int kk = 0; kk < 2; ++kk) {
            const int ko = kk * 16 + half * 8;
            const half8 a0 = *(const half8*)&sA[(wm + l31) * 32 + ko];
            const half8 a1 = *(const half8*)&sA[(wm + 32 + l31) * 32 + ko];
            const half8 b0 = *(const half8*)&sB[(wn + l31) * 32 + ko];
            const half8 b1 = *(const half8*)&sB[(wn + 32 + l31) * 32 + ko];
            acc[0][0] = __builtin_amdgcn_mfma_f32_32x32x16_f16(a0, b0, acc[0][0], 0, 0, 0);
            acc[0][1] = __builtin_amdgcn_mfma_f32_32x32x16_f16(a0, b1, acc[0][1], 0, 0, 0);
            acc[1][0] = __builtin_amdgcn_mfma_f32_32x32x16_f16(a1, b0, acc[1][0], 0, 0, 0);
            acc[1][1] = __builtin_amdgcn_mfma_f32_32x32x16_f16(a1, b1, acc[1][1], 0, 0, 0);
        }
    }
#pragma unroll
    for (int mm = 0; mm < 2; ++mm)
#pragma unroll
        for (int nn = 0; nn < 2; ++nn) {
            const int col = n0 + wn + nn * 32 + l31;
#pragma unroll
            for (int q = 0; q < 16; ++q) {
                const int row = m0 + wm + mm * 32 + (q & 3) + 8 * (q >> 2) + 4 * half;
                const size_t o = (size_t)row * N + col;
                const fp8_t e = enc_fp8(acc[mm][nn][q]);
                Ab8[o] = e;
                Ah[o] = e;     // initial Aeff (v=u=0)
            }
        }
}

// ---------------------------------------------------------------------------
// fp16 MFMA GEMM (one-shot, exact R0 core): dec = enc @ w via A=ench, B=whT
// ---------------------------------------------------------------------------
__global__ __launch_bounds__(256)
void mfma_nn_dec(const _Float16* __restrict__ A, const _Float16* __restrict__ B,
                 float* __restrict__ C, int N, int K) {
    __shared__ _Float16 sA[128 * 32];
    __shared__ _Float16 sB[128 * 32];
    const int tid = threadIdx.x;
    const int m0 = blockIdx.y * 128;
    const int n0 = blockIdx.x * 128;
    const int wv = tid >> 6, ln = tid & 63;
    const int half = ln >> 5, l31 = ln & 31;
    const int wm = (wv >> 1) * 64, wn = (wv & 1) * 64;
    const int r0 = tid >> 2, koff = (tid & 3) * 8;
    const size_t ga0 = (size_t)(m0 + r0) * K + koff;
    const size_t ga1 = (size_t)(m0 + r0 + 64) * K + koff;
    const size_t gb0 = (size_t)(n0 + r0) * K + koff;
    const size_t gb1 = (size_t)(n0 + r0 + 64) * K + koff;
    const int ldst0 = tid * 8, ldst1 = (256 + tid) * 8;

    floatx16 acc[2][2];
#pragma unroll
    for (int a = 0; a < 2; ++a)
#pragma unroll
        for (int b = 0; b < 2; ++b)
#pragma unroll
            for (int q = 0; q < 16; ++q) acc[a][b][q] = 0.f;

    for (int k = 0; k < K; k += 32) {
        __syncthreads();
        GLOAD_LDS16(A + ga0 + k, sA + ldst0);
        GLOAD_LDS16(A + ga1 + k, sA + ldst1);
        GLOAD_LDS16(B + gb0 + k, sB + ldst0);
        GLOAD_LDS16(B + gb1 + k, sB + ldst1);
        __syncthreads();
#pragma unroll
        for (int kk = 0; kk < 2; ++kk) {
            const int ko = kk * 16 + half * 8;
            const half8 a0 = *(const half8*)&sA[(wm + l31) * 32 + ko];
            const half8 a1 = *(const half8*)&sA[(wm + 32 + l31) * 32 + ko];
            const half8 b0 = *(const half8*)&sB[(wn + l31) * 32 + ko];
            const half8 b1 = *(const half8*)&sB[(wn + 32 + l31) * 32 + ko];
            acc[0][0] = __builtin_amdgcn_mfma_f32_32x32x16_f16(a0, b0, acc[0][0], 0, 0, 0);
            acc[0][1] = __builtin_amdgcn_mfma_f32_32x32x16_f16(a0, b1, acc[0][1], 0, 0, 0);
            acc[1][0] = __builtin_amdgcn_mfma_f32_32x32x16_f16(a1, b0, acc[1][0], 0, 0, 0);
            acc[1][1] = __builtin_amdgcn_mfma_f32_32x32x16_f16(a1, b1, acc[1][1], 0, 0, 0);
        }
    }
#pragma unroll
    for (int mm = 0; mm < 2; ++mm)
#pragma unroll
        for (int nn = 0; nn < 2; ++nn) {
            const int col = n0 + wn + nn * 32 + l31;
#pragma unroll
            for (int q = 0; q < 16; ++q) {
                const int row = m0 + wm + mm * 32 + (q & 3) + 8 * (q >> 2) + 4 * half;
                C[(size_t)row * N + col] = acc[mm][nn][q];
            }
        }
}

// ---------------------------------------------------------------------------
// fp8 MFMA GEMM (loop, exact R0 core): xk_part[kz] = Aeff @ (32*Minv) / 32.
// 128x128 tile, BK=64, KSPLIT=4, grid (16,8,4)=512 blocks = 2/CU.
// Stripe skip via ONE scalar flag load (parity-buffered; replaces the
// 128-int solved scan). Block (0,by,0) zeroes next-parity flags first.
// ---------------------------------------------------------------------------
__global__ __launch_bounds__(256)
void xk_mfma(const fp8_t* __restrict__ Ah, const fp8_t* __restrict__ BhT,
             fp8_t* __restrict__ xkp, const int* __restrict__ stripe_cur,
             int* __restrict__ stripe_nxt) {
    const int tid = threadIdx.x;
    // reset next-parity flags (before any possible early exit); update(t)
    // runs strictly after this dispatch completes (same-stream ordering).
    if (blockIdx.x == 0 && blockIdx.z == 0 && tid < 8) stripe_nxt[tid] = 0;
    if (stripe_cur[blockIdx.y] == 0) return;

    __shared__ fp8_t smem[16384];
    fp8_t* sA = smem;           // 8KB
    fp8_t* sB = smem + 8192;    // 8KB
    const int m0 = blockIdx.y * 128;
    const int n0 = blockIdx.x * 128;
    const int kz = blockIdx.z;
    constexpr size_t P = (size_t)BATCH * OUT_F;

    const int wv = tid >> 6;
    const int ln = tid & 63;
    const int half = ln >> 5;
    const int l31 = ln & 31;
    const int wm = (wv >> 1) * 64;
    const int wn = (wv & 1) * 64;

    const int r = tid & 127;
    const int c0 = tid >> 7;           // 0 or 1
    const fp8_t* gA = Ah  + (size_t)(m0 + r) * OUT_F + kz * KCHUNK;
    const fp8_t* gB = BhT + (size_t)(n0 + r) * OUT_F + kz * KCHUNK;
    fp8_t* lA0 = sA + (c0 * 128 + r) * 16;
    fp8_t* lA1 = sA + ((c0 + 2) * 128 + r) * 16;
    fp8_t* lB0 = sB + (c0 * 128 + r) * 16;
    fp8_t* lB1 = sB + ((c0 + 2) * 128 + r) * 16;

    floatx16 acc[2][2];
#pragma unroll
    for (int a = 0; a < 2; ++a)
#pragma unroll
        for (int b = 0; b < 2; ++b)
#pragma unroll
            for (int q = 0; q < 16; ++q) acc[a][b][q] = 0.f;

    const int ao0 = (wm + l31) * 16 + half * 8;
    const int ao1 = (wm + 32 + l31) * 16 + half * 8;
    const int bo0 = (wn + l31) * 16 + half * 8;
    const int bo1 = (wn + 32 + l31) * 16 + half * 8;

    for (int k = 0; k < KCHUNK; k += 64) {
        __syncthreads();
        GLOAD_LDS16(gA + k + c0 * 16, lA0);
        GLOAD_LDS16(gA + k + (c0 + 2) * 16, lA1);
        GLOAD_LDS16(gB + k + c0 * 16, lB0);
        GLOAD_LDS16(gB + k + (c0 + 2) * 16, lB1);
        __syncthreads();

#pragma unroll
        for (int kk = 0; kk < 4; ++kk) {
            const int cb = kk * 2048;
            const long long a0 = *(const long long*)&sA[cb + ao0];
            const long long a1 = *(const long long*)&sA[cb + ao1];
            const long long b0 = *(const long long*)&sB[cb + bo0];
            const long long b1 = *(const long long*)&sB[cb + bo1];
            acc[0][0] = __builtin_amdgcn_mfma_f32_32x32x16_fp8_fp8(a0, b0, acc[0][0], 0, 0, 0);
            acc[0][1] = __builtin_amdgcn_mfma_f32_32x32x16_fp8_fp8(a0, b1, acc[0][1], 0, 0, 0);
            acc[1][0] = __builtin_amdgcn_mfma_f32_32x32x16_fp8_fp8(a1, b0, acc[1][0], 0, 0, 0);
            acc[1][1] = __builtin_amdgcn_mfma_f32_32x32x16_fp8_fp8(a1, b1, acc[1][1], 0, 0, 0);
        }
    }

    // epilogue: scatter fp8 results into LDS tile, then coalesced 16B stores
    __syncthreads();
#pragma unroll
    for (int mm = 0; mm < 2; ++mm)
#pragma unroll
        for (int nn = 0; nn < 2; ++nn) {
            const int lcol = wn + nn * 32 + l31;
#pragma unroll
            for (int q = 0; q < 16; ++q) {
                const int lrow = wm + mm * 32 + (q & 3) + 8 * (q >> 2) + 4 * half;
                smem[lrow * 128 + lcol] = enc_fp8(acc[mm][nn][q] * BSCALE_INV);
            }
        }
    __syncthreads();
    fp8_t* outp = xkp + kz * P + (size_t)m0 * OUT_F + n0;
#pragma unroll
    for (int s = 0; s < 4; ++s) {
        const int f = (s * 256 + tid) * 16;
        *(int4*)&outp[(size_t)(f >> 7) * OUT_F + (f & 127)] = *(const int4*)&smem[f];
    }
}

// ---------------------------------------------------------------------------
// Update (exact R0 core + stripe flag): xk = sum of 4 fp8 partials;
// softshrink; u update; conv check; write next Aeff fp8. One block per row.
// Rows that remain unsolved set their stripe's next-parity activity flag.
// ---------------------------------------------------------------------------
__global__ __launch_bounds__(256)
void update_kernel(const fp8_t* __restrict__ xkp, const fp8_t* __restrict__ Ab8,
                   _Float16* __restrict__ v, _Float16* __restrict__ u,
                   float* __restrict__ enc, fp8_t* __restrict__ Ah,
                   int* __restrict__ solved, int* __restrict__ stripe_nxt) {
    const int row = blockIdx.x;
    if (solved[row]) return;
    const int t = threadIdx.x;
    constexpr size_t P = (size_t)BATCH * OUT_F;

    const int c = t * 8;
    const size_t off = (size_t)row * OUT_F + c;
    const int2 q0 = *(const int2*)&xkp[off];
    const int2 q1 = *(const int2*)&xkp[P + off];
    const int2 q2 = *(const int2*)&xkp[2 * P + off];
    const int2 q3 = *(const int2*)&xkp[3 * P + off];
    const half8 u8 = *(const half8*)&u[off];
    const half8 v8 = *(const half8*)&v[off];
    const int2 ab2 = *(const int2*)&Ab8[off];

    float f0[4], f1[4], f2[4], f3[4], g0[4], g1[4], g2[4], g3[4];
    cvt4_fp8(q0.x, f0); cvt4_fp8(q1.x, f1); cvt4_fp8(q2.x, f2); cvt4_fp8(q3.x, f3);
    cvt4_fp8(q0.y, g0); cvt4_fp8(q1.y, g1); cvt4_fp8(q2.y, g2); cvt4_fp8(q3.y, g3);
    float ab0[4], ab1[4];
    cvt4_fp8(ab2.x, ab0); cvt4_fp8(ab2.y, ab1);
    float xs[8], abv[8];
#pragma unroll
    for (int j = 0; j < 4; ++j) {
        xs[j] = f0[j] + f1[j] + f2[j] + f3[j];
        xs[j + 4] = g0[j] + g1[j] + g2[j] + g3[j];
        abv[j] = ab0[j];
        abv[j + 4] = ab1[j];
    }

    float vn_all[8], ae[8];
    half8 vo, uo;
    float dx2 = 0.f, xn2 = 0.f;
#pragma unroll
    for (int j = 0; j < 8; ++j) {
        const float xk = xs[j];
        const float uv = (float)u8[j];
        const float vp = (float)v8[j];
        const float z = xk + uv;
        const float az = fabsf(z) - LAMBD;
        const float vnew = az > 0.f ? copysignf(az, z) : 0.f;
        const float unew = uv + xk - vnew;
        const float d = vnew - vp;
        dx2 += d * d;
        xn2 += vnew * vnew;
        vn_all[j] = vnew;
        vo[j] = (_Float16)vnew;
        uo[j] = (_Float16)unew;
        ae[j] = abv[j] + vnew - unew;
    }
    *(half8*)&v[off] = vo;
    *(half8*)&u[off] = uo;
    int2 ah;
    ah.x = pk4_fp8(ae[0], ae[1], ae[2], ae[3]);
    ah.y = pk4_fp8(ae[4], ae[5], ae[6], ae[7]);
    *(int2*)&Ah[off] = ah;

#pragma unroll
    for (int o = 32; o > 0; o >>= 1) {
        dx2 += __shfl_down(dx2, o);
        xn2 += __shfl_down(xn2, o);
    }
    __shared__ float sdx[4], sxn[4];
    __shared__ float s_conv;
    if ((t & 63) == 0) { sdx[t >> 6] = dx2; sxn[t >> 6] = xn2; }
    __syncthreads();
    if (t == 0) {
        const float dxt = sqrtf(sdx[0] + sdx[1] + sdx[2] + sdx[3]);
        const float xnt = sqrtf(sxn[0] + sxn[1] + sxn[2] + sxn[3]);
        const bool conv = (dxt / xnt) < TOL;   // NaN -> false, matches jnp
        s_conv = conv ? 1.f : 0.f;
        if (conv) solved[row] = 1;
        else      stripe_nxt[row >> 7] = 1;    // stripe stays active next iter
    }
    __syncthreads();
    if (s_conv != 0.f) {
        *(float4*)&enc[off] = make_float4(vn_all[0], vn_all[1], vn_all[2], vn_all[3]);
        *(float4*)&enc[off + 4] = make_float4(vn_all[4], vn_all[5], vn_all[6], vn_all[7]);
    }
}

// ---------------------------------------------------------------------------
extern "C" void kernel_launch(void* const* d_in, const int* in_sizes, int n_in,
                              void* d_out, int out_size, void* d_ws, size_t ws_size,
                              hipStream_t stream) {
    (void)in_sizes; (void)n_in; (void)out_size; (void)ws_size;
    const float* x    = (const float*)d_in[0];   // 1024 x 1024
    const float* w    = (const float*)d_in[1];   // 2048 x 1024
    const float* Minv = (const float*)d_in[2];   // 2048 x 2048

    float* enc = (float*)d_out;                  // 1024 x 2048
    float* dec = enc + (size_t)BATCH * OUT_F;    // 1024 x 1024

    constexpr size_t P = (size_t)BATCH * OUT_F;  // 2M elements
    fp8_t* Ab8 = (fp8_t*)d_ws;                   // P fp8
    _Float16* v   = (_Float16*)(Ab8 + P);        // P f16
    _Float16* u   = v + P;                       // P f16
    _Float16* xh  = u + P;                       // 1M f16
    _Float16* wh  = xh + (size_t)BATCH * IN_F;   // 2M f16
    _Float16* whT = wh + (size_t)OUT_F * IN_F;   // 2M f16
    _Float16* ench = whT + (size_t)IN_F * OUT_F; // P f16
    fp8_t* Ah  = (fp8_t*)(ench + P);             // P fp8
    fp8_t* xkp = Ah + P;                         // 4P fp8
    fp8_t* BhT = xkp + 4 * P;                    // OUT_F^2 fp8 (4MB)
    int* solved = (int*)(BhT + (size_t)OUT_F * OUT_F);

    // stripe activity flags (2 parities x 8) in the dead ench region
    // (R3-proven scratch; overwritten only by the post-loop cast).
    int* stripe_act = (int*)ench;

    // merged setup: init + cast x + cast w + transpose w + Minv->fp8
    setup_kernel<<<NB_TOTAL, 256, 0, stream>>>(
        x, w, Minv, (float4*)v, (float4*)u, (float4*)enc, solved, stripe_act,
        xh, wh, whT, BhT);

    // Ab = x @ w^T (MFMA fp16) -> Ab8 fp8 + initial Aeff fp8
    mfma_nt_ab<<<dim3(OUT_F / 128, BATCH / 128), 256, 0, stream>>>(
        xh, wh, Ab8, Ah, OUT_F, IN_F);

    for (int it = 0; it < MAX_ITERS; ++it) {
        const int par = it & 1;
        xk_mfma<<<dim3(OUT_F / 128, BATCH / 128, KSPLIT), 256, 0, stream>>>(
            Ah, BhT, xkp, stripe_act + par * 8, stripe_act + (par ^ 1) * 8);
        update_kernel<<<BATCH, 256, 0, stream>>>(
            xkp, Ab8, v, u, enc, Ah, solved, stripe_act + (par ^ 1) * 8);
    }

    // decoded = encoded @ w (MFMA fp16) -- ench cast overwrites flag scratch
    // only after the loop is done with it.
    cast_f16_kernel<<<(BATCH * OUT_F / 4 + 255) / 256, 256, 0, stream>>>(enc, ench, BATCH * OUT_F);
    mfma_nn_dec<<<dim3(IN_F / 128, BATCH / 128), 256, 0, stream>>>(
        ench, whT, dec, IN_F, OUT_F);
}